// Round 18
// baseline (233.894 us; speedup 1.0000x reference)
//
#include <hip/hip_runtime.h>
#include <hip/hip_cooperative_groups.h>
#include <math.h>

namespace cg = cooperative_groups;

#define HW 4096
#define NCH 4
#define TPB 256                               // 4 waves/block
#define NBLOCKS 512                           // 2 blocks/CU guaranteed co-resident
#define ROWS_PER_ITER 16                      // rows per window iteration
#define KNN 5
#define WINB 544                              // shared window (ranks)

#define NBINS 512
#define BLO   (-6.0f)
#define BDELTA 0.0234375f      // 12/512, exact in fp32
#define BINV  (512.0f / 12.0f)
#define SLOP  1e-5f
#define INFT  3.4e38f

// ws layout (float idx): bxx[4][4096]@0, bxy@16384, by@32768,
// prefX int@49152 (4*513), prefY after it, partials@57344 (512 floats).
#define WS_BXY   16384
#define WS_BY    32768
#define WS_PREF  49152
#define WS_PART  57344

__device__ __forceinline__ int binOf(float v) {
    int b = (int)floorf((v - BLO) * BINV);
    return min(max(b, 0), NBINS - 1);
}

// digamma for positive integer args. Shift to >= 6 + asymptotic. ~1e-7.
__device__ __forceinline__ float digammaf_dev(float x) {
    float r = 0.f;
    while (x < 6.f) { r -= 1.f / x; x += 1.f; }
    float f = 1.f / x, f2 = f * f;
    return logf(x) - 0.5f * f
         - f2 * (1.f / 12.f - f2 * (1.f / 120.f - f2 * (1.f / 252.f))) + r;
}

// Insert d into ascending sorted 6-list (drop max): 6 independent med3.
__device__ __forceinline__ void insert6(float (&s)[6], float d) {
    float n0 = fminf(s[0], d);
    float n1 = __builtin_amdgcn_fmed3f(s[0], s[1], d);
    float n2 = __builtin_amdgcn_fmed3f(s[1], s[2], d);
    float n3 = __builtin_amdgcn_fmed3f(s[2], s[3], d);
    float n4 = __builtin_amdgcn_fmed3f(s[3], s[4], d);
    float n5 = __builtin_amdgcn_fmed3f(s[4], s[5], d);
    s[0] = n0; s[1] = n1; s[2] = n2; s[3] = n3; s[4] = n4; s[5] = n5;
}

__global__ __launch_bounds__(TPB, 4) void knnmi_all(const float* __restrict__ x,
                                                    const float* __restrict__ y,
                                                    float* __restrict__ ws,
                                                    float* __restrict__ out) {
    __shared__ float2 swin[WINB];         // 4.25 KB window
    __shared__ int pfys[NBINS + 1];       // 2.05 KB y-prefix table
    __shared__ int h[NBINS];              // 2 KB bucketize histogram
    __shared__ float red[ROWS_PER_ITER];

    cg::grid_group grid = cg::this_grid();

    // ================= phase 1: bucketize (blocks 0..7) ===================
    if (blockIdx.x < 2 * NCH) {
        const int c    = blockIdx.x >> 1;
        const int side = blockIdx.x & 1;  // 0 = X pairs, 1 = Y values
        const int t    = threadIdx.x;
        const float* src  = (side == 0 ? x : y) + c * HW;
        const float* ysrc = y + c * HW;
        int* pref = (int*)ws + WS_PREF + (side ? NCH * (NBINS + 1) : 0) + c * (NBINS + 1);

        for (int i = t; i < NBINS; i += TPB) h[i] = 0;
        __syncthreads();

        float vx[16], vy[16];
        int bn[16];
#pragma unroll
        for (int k = 0; k < 16; ++k) {
            int i = t + k * TPB;
            float v = src[i];
            vx[k] = v;
            vy[k] = (side == 0) ? ysrc[i] : 0.f;
            bn[k] = binOf(v);
            atomicAdd(&h[bn[k]], 1);
        }
        __syncthreads();

        if (t < 64) {                         // single-wave scan
            int sinc[8];
            sinc[0] = h[t * 8 + 0];
#pragma unroll
            for (int j = 1; j < 8; ++j) sinc[j] = sinc[j - 1] + h[t * 8 + j];
            int tot = sinc[7], inc = tot;
#pragma unroll
            for (int off = 1; off < 64; off <<= 1) {
                int u = __shfl_up(inc, off);
                if (t >= off) inc += u;
            }
            int ex = inc - tot;
#pragma unroll
            for (int j = 0; j < 8; ++j) {
                int st = ex + (j ? sinc[j - 1] : 0);
                h[t * 8 + j]    = st;
                pref[t * 8 + j] = st;
            }
            if (t == 63) pref[NBINS] = HW;
        }
        __syncthreads();

        if (side == 0) {
            float* bxx = ws + c * HW;
            float* bxy = ws + WS_BXY + c * HW;
#pragma unroll
            for (int k = 0; k < 16; ++k) {
                int pos = atomicAdd(&h[bn[k]], 1);
                bxx[pos] = vx[k];
                bxy[pos] = vy[k];
            }
        } else {
            float* by = ws + WS_BY + c * HW;
#pragma unroll
            for (int k = 0; k < 16; ++k) {
                int pos = atomicAdd(&h[bn[k]], 1);
                by[pos] = vx[k];
            }
        }
    }

    __threadfence();
    grid.sync();   // phase-1 writes visible device-wide

    // ================= phase 2: 2 x 16-row windows per block ==============
    const int c      = blockIdx.x >> 7;       // channel (128 blocks each)
    const int rbBase = (blockIdx.x & 127) * 2;
    const float* bxx = ws + c * HW;
    const float* bxy = ws + WS_BXY + c * HW;
    const float* by  = ws + WS_BY  + c * HW;
    const int* prefy = (const int*)ws + WS_PREF + NCH * (NBINS + 1) + c * (NBINS + 1);

    for (int i = threadIdx.x; i <= NBINS; i += TPB) pfys[i] = prefy[i];

    const int wv   = threadIdx.x >> 6;    // wave 0..3
    const int lane = threadIdx.x & 63;
    const int l    = lane & 15;           // lane within 16-lane group
    const int g    = lane >> 4;           // group (row) within wave
    const int q    = wv * 4 + g;          // 0..15

    float acc = 0.f;                      // thread-0 accumulator

    for (int t = 0; t < 2; ++t) {
        const int R0 = (rbBase + t) * ROWS_PER_ITER;

        int LO = R0 - 264;
        LO = max(LO, 0); LO = min(LO, HW - WINB); LO &= ~3;
        const int HI = LO + WINB;

        const float xLm1 = (LO > 0)  ? bxx[LO - 1] : 0.f;
        const float xHIv = (HI < HW) ? bxx[HI]     : 0.f;

        if (threadIdx.x < WINB / 4) {
            float4 xv = ((const float4*)(bxx + LO))[threadIdx.x];
            float4 yv = ((const float4*)(bxy + LO))[threadIdx.x];
            ((float4*)swin)[2 * threadIdx.x]     = make_float4(xv.x, yv.x, xv.y, yv.y);
            ((float4*)swin)[2 * threadIdx.x + 1] = make_float4(xv.z, yv.z, xv.w, yv.w);
        }
        __syncthreads();

        const int p = R0 + q;
        const float xi = swin[p - LO].x;
        const float yi = swin[p - LO].y;

        float s[6];
#pragma unroll
        for (int k = 0; k < 6; ++k) s[k] = INFT;

        const float4* f4 = (const float4*)swin;
#pragma unroll 4
        for (int it = 0; it < WINB / 32; ++it) {
            float4 pp = f4[it * 16 + l];
            insert6(s, fmaxf(fabsf(xi - pp.x), fabsf(yi - pp.y)));
            insert6(s, fmaxf(fabsf(xi - pp.z), fabsf(yi - pp.w)));
        }

#pragma unroll
        for (int m = 1; m < 16; m <<= 1) {
            float o[6];
#pragma unroll
            for (int k = 0; k < 6; ++k) o[k] = __shfl_xor(s[k], m);
#pragma unroll
            for (int k = 0; k < 6; ++k) insert6(s, o[k]);
        }
        float eps = s[5];

        float eL = INFT, eR = INFT;
        if (LO > 0) {
            int b = binOf(xLm1);
            eL = xi - (BLO + (float)(b + 1) * BDELTA + SLOP);
        }
        if (HI < HW) {
            int b = binOf(xHIv);
            eR = (BLO + (float)b * BDELTA - SLOP) - xi;
        }
        const bool ok = (eps <= eL) && (eps <= eR);

        int nx = 0, ny = 0;
        bool fell = false;
        unsigned long long bad = __ballot((l == 0) && !ok);
        while (bad) {
            int bit = (int)__ffsll(bad) - 1;
            bad &= bad - 1;
            const int tg = bit >> 4;
            const float xt = swin[(R0 + wv * 4 + tg) - LO].x;
            const float yt = swin[(R0 + wv * 4 + tg) - LO].y;
            float s3[6];
#pragma unroll
            for (int k = 0; k < 6; ++k) s3[k] = INFT;
            for (int it = 0; it < HW / 256; ++it) {
                float4 xv = ((const float4*)bxx)[it * 64 + lane];
                float4 yv = ((const float4*)bxy)[it * 64 + lane];
                insert6(s3, fmaxf(fabsf(xt - xv.x), fabsf(yt - yv.x)));
                insert6(s3, fmaxf(fabsf(xt - xv.y), fabsf(yt - yv.y)));
                insert6(s3, fmaxf(fabsf(xt - xv.z), fabsf(yt - yv.z)));
                insert6(s3, fmaxf(fabsf(xt - xv.w), fabsf(yt - yv.w)));
            }
#pragma unroll
            for (int m = 1; m < 64; m <<= 1) {
                float o[6];
#pragma unroll
                for (int k = 0; k < 6; ++k) o[k] = __shfl_xor(s3[k], m);
#pragma unroll
                for (int k = 0; k < 6; ++k) insert6(s3, o[k]);
            }
            const float e3 = s3[5];
            int cx = 0, cy = 0;
            for (int it = 0; it < HW / 256; ++it) {
                float4 xv = ((const float4*)bxx)[it * 64 + lane];
                float4 yv = ((const float4*)bxy)[it * 64 + lane];
                cx += (fabsf(xt - xv.x) < e3) + (fabsf(xt - xv.y) < e3)
                    + (fabsf(xt - xv.z) < e3) + (fabsf(xt - xv.w) < e3);
                cy += (fabsf(yt - yv.x) < e3) + (fabsf(yt - yv.y) < e3)
                    + (fabsf(yt - yv.z) < e3) + (fabsf(yt - yv.w) < e3);
            }
            int pk3 = (cx << 16) | cy;
#pragma unroll
            for (int m = 1; m < 64; m <<= 1) pk3 += __shfl_xor(pk3, m);
            if (g == tg) { eps = e3; nx = pk3 >> 16; ny = pk3 & 0xffff; fell = true; }
        }

        if (!fell) {
            // nx: every fl|dx| < eps point is inside the window (ok-check).
#pragma unroll 4
            for (int it = 0; it < WINB / 32; ++it) {
                float4 pp = f4[it * 16 + l];
                nx += (fabsf(xi - pp.x) < eps) + (fabsf(xi - pp.z) < eps);
            }
            // ny: interior via LDS prefix-diff + boundary scan from L2.
            int loB = binOf(yi - eps), hiB = binOf(yi + eps);
            int fLo = loB + 2, fHi = hiB - 2;
            if (fLo <= fHi) {
                if (l == 0) ny += pfys[fHi + 1] - pfys[fLo];
                int a0 = pfys[max(loB - 1, 0)], a1 = pfys[min(loB + 1, NBINS - 1) + 1];
                int b0 = pfys[max(hiB - 1, 0)], b1 = pfys[min(hiB + 1, NBINS - 1) + 1];
                for (int tt = a0 + l; tt < a1; tt += 16) ny += (fabsf(by[tt] - yi) < eps);
                for (int tt = b0 + l; tt < b1; tt += 16) ny += (fabsf(by[tt] - yi) < eps);
            } else {
                int a0 = pfys[max(loB - 1, 0)], a1 = pfys[min(hiB + 1, NBINS - 1) + 1];
                for (int tt = a0 + l; tt < a1; tt += 16) ny += (fabsf(by[tt] - yi) < eps);
            }
        }

        if (fell && l != 0) { nx = 0; ny = 0; }
        int pk = (nx << 16) | ny;
#pragma unroll
        for (int m = 1; m < 16; m <<= 1) pk += __shfl_xor(pk, m);

        if (l == 0)
            red[q] = digammaf_dev((float)(pk >> 16)) + digammaf_dev((float)(pk & 0xffff));
        __syncthreads();

        if (threadIdx.x == 0) {
            float v = 0.f;
#pragma unroll
            for (int k = 0; k < ROWS_PER_ITER; ++k) v += red[k];
            acc += v;
        }
    }

    if (threadIdx.x == 0) (ws + WS_PART)[blockIdx.x] = acc;

    __threadfence();
    grid.sync();   // partials visible device-wide

    // ================= phase 3: finalize (block 0) ========================
    if (blockIdx.x == 0) {
        const float* partials = ws + WS_PART;
        const int w    = threadIdx.x >> 6;    // wave = channel
        const int lane2 = threadIdx.x & 63;
        float sum = 0.f;
#pragma unroll
        for (int i = lane2; i < 128; i += 64)
            sum += partials[w * 128 + i];
#pragma unroll
        for (int m = 32; m; m >>= 1) sum += __shfl_xor(sum, m);
        if (lane2 == 0) {
            float mi = digammaf_dev((float)KNN) + digammaf_dev((float)HW)
                     - sum / (float)HW;
            out[w] = fmaxf(mi, 0.f);
        }
    }
}

extern "C" void kernel_launch(void* const* d_in, const int* in_sizes, int n_in,
                              void* d_out, int out_size, void* d_ws, size_t ws_size,
                              hipStream_t stream) {
    const float* x = (const float*)d_in[0];
    const float* y = (const float*)d_in[1];
    float* out = (float*)d_out;
    float* ws  = (float*)d_ws;   // all read regions fully rewritten every call

    void* args[] = {(void*)&x, (void*)&y, (void*)&ws, (void*)&out};
    hipLaunchCooperativeKernel((const void*)knnmi_all, dim3(NBLOCKS), dim3(TPB),
                               args, 0, stream);
}

// Round 19
// 46.192 us; speedup vs baseline: 5.0636x; 5.0636x over previous
//
#include <hip/hip_runtime.h>
#include <math.h>

#define HW 4096
#define NCH 4
#define TPB 256                               // 4 waves/block
#define ROWS_PER_BLOCK 16                     // contiguous rows, G=16
#define BLOCKS_PER_CH 256
#define NBLOCKS (NCH * BLOCKS_PER_CH)         // 1024
#define KNN 5
#define WINB 704                              // shared block window (ranks)

#define NBINS 512
#define BLO   (-6.0f)
#define BDELTA 0.0234375f      // 12/512, exact in fp32
#define BINV  (512.0f / 12.0f)
#define SLOP  1e-5f            // >> fp rounding of bin/edge math, << BDELTA
#define INFT  3.4e38f

// ws layout (float idx): bxx[4][4096]@0, bxy@16384, by@32768,
// prefX int@49152 (4*513), prefY after it, partials@57344 (1024 floats),
// done-counter int@58368.
#define WS_BXY   16384
#define WS_BY    32768
#define WS_PREF  49152
#define WS_PART  57344
#define WS_CNT   58368

__device__ __forceinline__ int binOf(float v) {
    int b = (int)floorf((v - BLO) * BINV);
    return min(max(b, 0), NBINS - 1);
}

// digamma for positive integer args. Shift to >= 6 + asymptotic. ~1e-7.
__device__ __forceinline__ float digammaf_dev(float x) {
    float r = 0.f;
    while (x < 6.f) { r -= 1.f / x; x += 1.f; }
    float f = 1.f / x, f2 = f * f;
    return logf(x) - 0.5f * f
         - f2 * (1.f / 12.f - f2 * (1.f / 120.f - f2 * (1.f / 252.f))) + r;
}

// Insert d into ascending sorted 6-list (drop max): 6 independent med3.
__device__ __forceinline__ void insert6(float (&s)[6], float d) {
    float n0 = fminf(s[0], d);
    float n1 = __builtin_amdgcn_fmed3f(s[0], s[1], d);
    float n2 = __builtin_amdgcn_fmed3f(s[1], s[2], d);
    float n3 = __builtin_amdgcn_fmed3f(s[2], s[3], d);
    float n4 = __builtin_amdgcn_fmed3f(s[3], s[4], d);
    float n5 = __builtin_amdgcn_fmed3f(s[4], s[5], d);
    s[0] = n0; s[1] = n1; s[2] = n2; s[3] = n3; s[4] = n4; s[5] = n5;
}

// --------- Kernel 0: bucketize; 8 blocks = (channel x side) ----------------
__global__ __launch_bounds__(256) void knnmi_bucketize(const float* __restrict__ x,
                                                       const float* __restrict__ y,
                                                       float* __restrict__ ws) {
    __shared__ int h[NBINS];          // histogram, then running starts
    const int c    = blockIdx.x >> 1;
    const int side = blockIdx.x & 1;  // 0 = X pairs, 1 = Y values
    const int t    = threadIdx.x;
    const float* src  = (side == 0 ? x : y) + c * HW;
    const float* ysrc = y + c * HW;
    int* pref = (int*)ws + WS_PREF + (side ? NCH * (NBINS + 1) : 0) + c * (NBINS + 1);

    if (blockIdx.x == 0 && t == 0)
        atomicExch((int*)ws + WS_CNT, 0);     // deterministic counter reset

    for (int i = t; i < NBINS; i += 256) h[i] = 0;
    __syncthreads();

    float vx[16], vy[16];
    int bn[16];
#pragma unroll
    for (int k = 0; k < 16; ++k) {            // one read pass, regs hold all
        int i = t + k * 256;
        float v = src[i];
        vx[k] = v;
        vy[k] = (side == 0) ? ysrc[i] : 0.f;
        bn[k] = binOf(v);
        atomicAdd(&h[bn[k]], 1);
    }
    __syncthreads();

    if (t < 64) {                             // single-wave scan, no barriers
        int sinc[8];
        sinc[0] = h[t * 8 + 0];
#pragma unroll
        for (int j = 1; j < 8; ++j) sinc[j] = sinc[j - 1] + h[t * 8 + j];
        int tot = sinc[7], inc = tot;
#pragma unroll
        for (int off = 1; off < 64; off <<= 1) {
            int u = __shfl_up(inc, off);
            if (t >= off) inc += u;
        }
        int ex = inc - tot;                   // exclusive prefix across lanes
#pragma unroll
        for (int j = 0; j < 8; ++j) {
            int st = ex + (j ? sinc[j - 1] : 0);
            h[t * 8 + j]    = st;
            pref[t * 8 + j] = st;
        }
        if (t == 63) pref[NBINS] = HW;
    }
    __syncthreads();

    if (side == 0) {
        float* bxx = ws + c * HW;
        float* bxy = ws + WS_BXY + c * HW;
#pragma unroll
        for (int k = 0; k < 16; ++k) {
            int pos = atomicAdd(&h[bn[k]], 1);
            bxx[pos] = vx[k];
            bxy[pos] = vy[k];
        }
    } else {
        float* by = ws + WS_BY + c * HW;
#pragma unroll
        for (int k = 0; k < 16; ++k) {
            int pos = atomicAdd(&h[bn[k]], 1);
            by[pos] = vx[k];
        }
    }
}

// --------- Kernel 1: windowed rows + fused last-block finalize -------------
__global__ __launch_bounds__(TPB, 4) void knnmi_rows(float* __restrict__ ws,
                                                     float* __restrict__ out) {
    __shared__ float2 swin[WINB];         // 5.5 KB shared window
    __shared__ int pfy[NBINS + 1];        // 2.05 KB y-prefix table
    __shared__ float red[ROWS_PER_BLOCK];
    __shared__ int lastFlag;

    const int c  = blockIdx.x >> 8;       // channel
    const int rb = blockIdx.x & 255;      // block within channel
    const int R0 = rb * ROWS_PER_BLOCK;   // first (contiguous) row
    const float* bxx = ws + c * HW;
    const float* bxy = ws + WS_BXY + c * HW;
    const float* by  = ws + WS_BY  + c * HW;
    const int* prefy = (const int*)ws + WS_PREF + NCH * (NBINS + 1) + c * (NBINS + 1);

    // Shared window [LO, LO+WINB): ~+-330 rank margin around the 16 rows.
    int LO = R0 - 344;
    LO = max(LO, 0); LO = min(LO, HW - WINB); LO &= ~3;   // float4-aligned
    const int HI = LO + WINB;

    // Edge sentinels issued early (latency hides under staging + pass 1).
    const float xLm1 = (LO > 0)  ? bxx[LO - 1] : 0.f;
    const float xHIv = (HI < HW) ? bxx[HI]     : 0.f;

    if (threadIdx.x < WINB / 4) {         // stage 176 float4-pairs
        float4 xv = ((const float4*)(bxx + LO))[threadIdx.x];
        float4 yv = ((const float4*)(bxy + LO))[threadIdx.x];
        ((float4*)swin)[2 * threadIdx.x]     = make_float4(xv.x, yv.x, xv.y, yv.y);
        ((float4*)swin)[2 * threadIdx.x + 1] = make_float4(xv.z, yv.z, xv.w, yv.w);
    }
    for (int i = threadIdx.x; i <= NBINS; i += TPB) pfy[i] = prefy[i];
    __syncthreads();

    const int wv   = threadIdx.x >> 6;    // wave 0..3
    const int lane = threadIdx.x & 63;
    const int l    = lane & 15;           // lane within 16-lane group
    const int g    = lane >> 4;           // group (row) within wave
    const int q    = wv * 4 + g;          // 0..15
    const int p    = R0 + q;              // this group's row

    const float xi = swin[p - LO].x;
    const float yi = swin[p - LO].y;

    float s[6];
#pragma unroll
    for (int k = 0; k < 6; ++k) s[k] = INFT;

    // Pass 1: whole window, 22 x ds_read_b128 (broadcast across groups).
    const float4* f4 = (const float4*)swin;
#pragma unroll 4
    for (int it = 0; it < WINB / 32; ++it) {
        float4 pp = f4[it * 16 + l];
        insert6(s, fmaxf(fabsf(xi - pp.x), fabsf(yi - pp.y)));
        insert6(s, fmaxf(fabsf(xi - pp.z), fabsf(yi - pp.w)));
    }

    // Merge 16 per-lane sorted 6-lists (4 butterfly stages).
#pragma unroll
    for (int m = 1; m < 16; m <<= 1) {
        float o[6];
#pragma unroll
        for (int k = 0; k < 6; ++k) o[k] = __shfl_xor(s[k], m);
#pragma unroll
        for (int k = 0; k < 6; ++k) insert6(s, o[k]);
    }
    float eps = s[5];    // candidate (k+1)-th smallest (window-local)

    // Exactness check: unscanned j have fl|xi-xj| >= bin-edge bound.
    float eL = INFT, eR = INFT;
    if (LO > 0) {
        int b = binOf(xLm1);
        eL = xi - (BLO + (float)(b + 1) * BDELTA + SLOP);
    }
    if (HI < HW) {
        int b = binOf(xHIv);
        eR = (BLO + (float)b * BDELTA - SLOP) - xi;
    }
    const bool ok = (eps <= eL) && (eps <= eR);

    // Rare (<~1% at WINB=704) fallback: whole-wave exact brute scan + counts.
    int nx = 0, ny = 0;
    bool fell = false;
    unsigned long long bad = __ballot((l == 0) && !ok);
    while (bad) {
        int bit = (int)__ffsll(bad) - 1;
        bad &= bad - 1;
        const int tg = bit >> 4;                      // failed group in wave
        const float xt = swin[(R0 + wv * 4 + tg) - LO].x;
        const float yt = swin[(R0 + wv * 4 + tg) - LO].y;
        float s3[6];
#pragma unroll
        for (int k = 0; k < 6; ++k) s3[k] = INFT;
        for (int it = 0; it < HW / 256; ++it) {       // pass A: eps, 16 iters
            float4 xv = ((const float4*)bxx)[it * 64 + lane];
            float4 yv = ((const float4*)bxy)[it * 64 + lane];
            insert6(s3, fmaxf(fabsf(xt - xv.x), fabsf(yt - yv.x)));
            insert6(s3, fmaxf(fabsf(xt - xv.y), fabsf(yt - yv.y)));
            insert6(s3, fmaxf(fabsf(xt - xv.z), fabsf(yt - yv.z)));
            insert6(s3, fmaxf(fabsf(xt - xv.w), fabsf(yt - yv.w)));
        }
#pragma unroll
        for (int m = 1; m < 64; m <<= 1) {
            float o[6];
#pragma unroll
            for (int k = 0; k < 6; ++k) o[k] = __shfl_xor(s3[k], m);
#pragma unroll
            for (int k = 0; k < 6; ++k) insert6(s3, o[k]);
        }
        const float e3 = s3[5];                       // exact global 6th
        int cx = 0, cy = 0;
        for (int it = 0; it < HW / 256; ++it) {       // pass B: counts (L2-hot)
            float4 xv = ((const float4*)bxx)[it * 64 + lane];
            float4 yv = ((const float4*)bxy)[it * 64 + lane];
            cx += (fabsf(xt - xv.x) < e3) + (fabsf(xt - xv.y) < e3)
                + (fabsf(xt - xv.z) < e3) + (fabsf(xt - xv.w) < e3);
            cy += (fabsf(yt - yv.x) < e3) + (fabsf(yt - yv.y) < e3)
                + (fabsf(yt - yv.z) < e3) + (fabsf(yt - yv.w) < e3);
        }
        int pk3 = (cx << 16) | cy;
#pragma unroll
        for (int m = 1; m < 64; m <<= 1) pk3 += __shfl_xor(pk3, m);
        if (g == tg) { eps = e3; nx = pk3 >> 16; ny = pk3 & 0xffff; fell = true; }
    }

    if (!fell) {
        // nx: ok-check guarantees every fl|dx| < eps point is inside the
        // staged window -> pure LDS scan, zero global.
#pragma unroll 4
        for (int it = 0; it < WINB / 32; ++it) {
            float4 pp = f4[it * 16 + l];
            nx += (fabsf(xi - pp.x) < eps) + (fabsf(xi - pp.z) < eps);
        }
        // ny: interior bins by LDS prefix-diff + boundary scan from L2.
        int loB = binOf(yi - eps), hiB = binOf(yi + eps);
        int fLo = loB + 2, fHi = hiB - 2;
        if (fLo <= fHi) {
            if (l == 0) ny += pfy[fHi + 1] - pfy[fLo];
            int a0 = pfy[max(loB - 1, 0)], a1 = pfy[min(loB + 1, NBINS - 1) + 1];
            int b0 = pfy[max(hiB - 1, 0)], b1 = pfy[min(hiB + 1, NBINS - 1) + 1];
            for (int tt = a0 + l; tt < a1; tt += 16) ny += (fabsf(by[tt] - yi) < eps);
            for (int tt = b0 + l; tt < b1; tt += 16) ny += (fabsf(by[tt] - yi) < eps);
        } else {
            int a0 = pfy[max(loB - 1, 0)], a1 = pfy[min(hiB + 1, NBINS - 1) + 1];
            for (int tt = a0 + l; tt < a1; tt += 16) ny += (fabsf(by[tt] - yi) < eps);
        }
    }

    // Group-reduce; fallback rows carry full counts on l==0 only.
    if (fell && l != 0) { nx = 0; ny = 0; }
    int pk = (nx << 16) | ny;                 // totals <= 4096, no carry
#pragma unroll
    for (int m = 1; m < 16; m <<= 1) pk += __shfl_xor(pk, m);

    if (l == 0)
        red[q] = digammaf_dev((float)(pk >> 16)) + digammaf_dev((float)(pk & 0xffff));
    __syncthreads();

    if (threadIdx.x == 0) {
        float v = 0.f;
#pragma unroll
        for (int k = 0; k < ROWS_PER_BLOCK; ++k) v += red[k];
        (ws + WS_PART)[blockIdx.x] = v;
        __threadfence();                      // partial visible device-wide
        int prev = atomicAdd((int*)ws + WS_CNT, 1);
        lastFlag = (prev == NBLOCKS - 1);
    }
    __syncthreads();

    // Last finishing block folds the 1024 partials -> out (saves a launch).
    if (lastFlag) {
        __threadfence();                      // acquire: see all partials
        const float* partials = ws + WS_PART;
        const int w = wv;                     // wave = channel
        float sum = 0.f;
#pragma unroll
        for (int i = lane; i < BLOCKS_PER_CH; i += 64)
            sum += partials[w * BLOCKS_PER_CH + i];
#pragma unroll
        for (int m = 32; m; m >>= 1) sum += __shfl_xor(sum, m);
        if (lane == 0) {
            float mi = digammaf_dev((float)KNN) + digammaf_dev((float)HW)
                     - sum / (float)HW;
            out[w] = fmaxf(mi, 0.f);
        }
    }
}

extern "C" void kernel_launch(void* const* d_in, const int* in_sizes, int n_in,
                              void* d_out, int out_size, void* d_ws, size_t ws_size,
                              hipStream_t stream) {
    const float* x = (const float*)d_in[0];
    const float* y = (const float*)d_in[1];
    float* out = (float*)d_out;
    float* ws  = (float*)d_ws;   // all read regions fully rewritten every call

    knnmi_bucketize<<<2 * NCH, 256, 0, stream>>>(x, y, ws);
    knnmi_rows<<<NBLOCKS, TPB, 0, stream>>>(ws, out);
}

// Round 20
// 32.657 us; speedup vs baseline: 7.1622x; 1.4145x over previous
//
#include <hip/hip_runtime.h>
#include <math.h>

#define HW 4096
#define NCH 4
#define TPB 1024                              // 16 waves/block
#define ROWS_PER_BLOCK 64                     // contiguous rows, G=16
#define BLOCKS_PER_CH 64
#define NBLOCKS (NCH * BLOCKS_PER_CH)         // 256
#define KNN 5
#define WINB 704                              // shared block window (ranks)

#define NBINS 512
#define BLO   (-6.0f)
#define BDELTA 0.0234375f      // 12/512, exact in fp32
#define BINV  (512.0f / 12.0f)
#define SLOP  1e-5f            // >> fp rounding of bin/edge math, << BDELTA
#define INFT  3.4e38f

// ws layout (float idx): bxx[4][4096]@0, bxy@16384, by@32768,
// prefX int@49152 (4*513), prefY after it, partials@57344 (256 floats).
#define WS_BXY   16384
#define WS_BY    32768
#define WS_PREF  49152
#define WS_PART  57344

__device__ __forceinline__ int binOf(float v) {
    int b = (int)floorf((v - BLO) * BINV);
    return min(max(b, 0), NBINS - 1);
}

// digamma for positive integer args. Shift to >= 6 + asymptotic. ~1e-7.
__device__ __forceinline__ float digammaf_dev(float x) {
    float r = 0.f;
    while (x < 6.f) { r -= 1.f / x; x += 1.f; }
    float f = 1.f / x, f2 = f * f;
    return logf(x) - 0.5f * f
         - f2 * (1.f / 12.f - f2 * (1.f / 120.f - f2 * (1.f / 252.f))) + r;
}

// Insert d into ascending sorted 6-list (drop max): 6 independent med3.
__device__ __forceinline__ void insert6(float (&s)[6], float d) {
    float n0 = fminf(s[0], d);
    float n1 = __builtin_amdgcn_fmed3f(s[0], s[1], d);
    float n2 = __builtin_amdgcn_fmed3f(s[1], s[2], d);
    float n3 = __builtin_amdgcn_fmed3f(s[2], s[3], d);
    float n4 = __builtin_amdgcn_fmed3f(s[3], s[4], d);
    float n5 = __builtin_amdgcn_fmed3f(s[4], s[5], d);
    s[0] = n0; s[1] = n1; s[2] = n2; s[3] = n3; s[4] = n4; s[5] = n5;
}

// --------- Kernel 0: bucketize; 8 blocks = (channel x side) ----------------
__global__ __launch_bounds__(256) void knnmi_bucketize(const float* __restrict__ x,
                                                       const float* __restrict__ y,
                                                       float* __restrict__ ws) {
    __shared__ int h[NBINS];          // histogram, then running starts
    const int c    = blockIdx.x >> 1;
    const int side = blockIdx.x & 1;  // 0 = X pairs, 1 = Y values
    const int t    = threadIdx.x;
    const float* src  = (side == 0 ? x : y) + c * HW;
    const float* ysrc = y + c * HW;
    int* pref = (int*)ws + WS_PREF + (side ? NCH * (NBINS + 1) : 0) + c * (NBINS + 1);

    for (int i = t; i < NBINS; i += 256) h[i] = 0;
    __syncthreads();

    float vx[16], vy[16];
    int bn[16];
#pragma unroll
    for (int k = 0; k < 16; ++k) {            // one read pass, regs hold all
        int i = t + k * 256;
        float v = src[i];
        vx[k] = v;
        vy[k] = (side == 0) ? ysrc[i] : 0.f;
        bn[k] = binOf(v);
        atomicAdd(&h[bn[k]], 1);
    }
    __syncthreads();

    if (t < 64) {                             // single-wave scan, no barriers
        int sinc[8];
        sinc[0] = h[t * 8 + 0];
#pragma unroll
        for (int j = 1; j < 8; ++j) sinc[j] = sinc[j - 1] + h[t * 8 + j];
        int tot = sinc[7], inc = tot;
#pragma unroll
        for (int off = 1; off < 64; off <<= 1) {
            int u = __shfl_up(inc, off);
            if (t >= off) inc += u;
        }
        int ex = inc - tot;                   // exclusive prefix across lanes
#pragma unroll
        for (int j = 0; j < 8; ++j) {
            int st = ex + (j ? sinc[j - 1] : 0);
            h[t * 8 + j]    = st;
            pref[t * 8 + j] = st;
        }
        if (t == 63) pref[NBINS] = HW;
    }
    __syncthreads();

    if (side == 0) {
        float* bxx = ws + c * HW;
        float* bxy = ws + WS_BXY + c * HW;
#pragma unroll
        for (int k = 0; k < 16; ++k) {
            int pos = atomicAdd(&h[bn[k]], 1);
            bxx[pos] = vx[k];
            bxy[pos] = vy[k];
        }
    } else {
        float* by = ws + WS_BY + c * HW;
#pragma unroll
        for (int k = 0; k < 16; ++k) {
            int pos = atomicAdd(&h[bn[k]], 1);
            by[pos] = vx[k];
        }
    }
}

// --------- Kernel 1: 64 rows/block, one staged window, 256 blocks ----------
__global__ __launch_bounds__(TPB, 4) void knnmi_rows(float* __restrict__ ws) {
    __shared__ float2 swin[WINB];         // 5.5 KB shared window
    __shared__ int pfy[NBINS + 1];        // 2.05 KB y-prefix table
    __shared__ float red[ROWS_PER_BLOCK];

    const int c  = blockIdx.x >> 6;       // channel (64 blocks each)
    const int rb = blockIdx.x & 63;       // block within channel
    const int R0 = rb * ROWS_PER_BLOCK;   // first of 64 contiguous rows
    const float* bxx = ws + c * HW;
    const float* bxy = ws + WS_BXY + c * HW;
    const float* by  = ws + WS_BY  + c * HW;
    const int* prefy = (const int*)ws + WS_PREF + NCH * (NBINS + 1) + c * (NBINS + 1);

    // Shared window [LO, LO+WINB): rows span [R0, R0+64); margin ~320/side.
    int LO = R0 - 320;
    LO = max(LO, 0); LO = min(LO, HW - WINB); LO &= ~3;   // float4-aligned
    const int HI = LO + WINB;

    // Edge sentinels issued early (latency hides under staging + pass 1).
    const float xLm1 = (LO > 0)  ? bxx[LO - 1] : 0.f;
    const float xHIv = (HI < HW) ? bxx[HI]     : 0.f;

    if (threadIdx.x < WINB / 4) {         // stage 176 float4-pairs
        float4 xv = ((const float4*)(bxx + LO))[threadIdx.x];
        float4 yv = ((const float4*)(bxy + LO))[threadIdx.x];
        ((float4*)swin)[2 * threadIdx.x]     = make_float4(xv.x, yv.x, xv.y, yv.y);
        ((float4*)swin)[2 * threadIdx.x + 1] = make_float4(xv.z, yv.z, xv.w, yv.w);
    }
    if (threadIdx.x <= NBINS) pfy[threadIdx.x] = prefy[threadIdx.x];
    __syncthreads();

    const int wv   = threadIdx.x >> 6;    // wave 0..15
    const int lane = threadIdx.x & 63;
    const int l    = lane & 15;           // lane within 16-lane group
    const int g    = lane >> 4;           // group (row) within wave
    const int q    = wv * 4 + g;          // 0..63
    const int p    = R0 + q;              // this group's row

    const float xi = swin[p - LO].x;
    const float yi = swin[p - LO].y;

    float s[6];
#pragma unroll
    for (int k = 0; k < 6; ++k) s[k] = INFT;

    // Pass 1: whole window, 22 x ds_read_b128 (broadcast across groups).
    const float4* f4 = (const float4*)swin;
#pragma unroll 4
    for (int it = 0; it < WINB / 32; ++it) {
        float4 pp = f4[it * 16 + l];
        insert6(s, fmaxf(fabsf(xi - pp.x), fabsf(yi - pp.y)));
        insert6(s, fmaxf(fabsf(xi - pp.z), fabsf(yi - pp.w)));
    }

    // Merge 16 per-lane sorted 6-lists (4 butterfly stages).
#pragma unroll
    for (int m = 1; m < 16; m <<= 1) {
        float o[6];
#pragma unroll
        for (int k = 0; k < 6; ++k) o[k] = __shfl_xor(s[k], m);
#pragma unroll
        for (int k = 0; k < 6; ++k) insert6(s, o[k]);
    }
    float eps = s[5];    // candidate (k+1)-th smallest (window-local)

    // Exactness check: unscanned j have fl|xi-xj| >= bin-edge bound.
    float eL = INFT, eR = INFT;
    if (LO > 0) {
        int b = binOf(xLm1);
        eL = xi - (BLO + (float)(b + 1) * BDELTA + SLOP);
    }
    if (HI < HW) {
        int b = binOf(xHIv);
        eR = (BLO + (float)b * BDELTA - SLOP) - xi;
    }
    const bool ok = (eps <= eL) && (eps <= eR);

    // Rare fallback: whole-wave exact brute scan of all 4096 + counts.
    int nx = 0, ny = 0;
    bool fell = false;
    unsigned long long bad = __ballot((l == 0) && !ok);
    while (bad) {
        int bit = (int)__ffsll(bad) - 1;
        bad &= bad - 1;
        const int tg = bit >> 4;                      // failed group in wave
        const float xt = swin[(R0 + wv * 4 + tg) - LO].x;
        const float yt = swin[(R0 + wv * 4 + tg) - LO].y;
        float s3[6];
#pragma unroll
        for (int k = 0; k < 6; ++k) s3[k] = INFT;
        for (int it = 0; it < HW / 256; ++it) {       // pass A: eps, 16 iters
            float4 xv = ((const float4*)bxx)[it * 64 + lane];
            float4 yv = ((const float4*)bxy)[it * 64 + lane];
            insert6(s3, fmaxf(fabsf(xt - xv.x), fabsf(yt - yv.x)));
            insert6(s3, fmaxf(fabsf(xt - xv.y), fabsf(yt - yv.y)));
            insert6(s3, fmaxf(fabsf(xt - xv.z), fabsf(yt - yv.z)));
            insert6(s3, fmaxf(fabsf(xt - xv.w), fabsf(yt - yv.w)));
        }
#pragma unroll
        for (int m = 1; m < 64; m <<= 1) {
            float o[6];
#pragma unroll
            for (int k = 0; k < 6; ++k) o[k] = __shfl_xor(s3[k], m);
#pragma unroll
            for (int k = 0; k < 6; ++k) insert6(s3, o[k]);
        }
        const float e3 = s3[5];                       // exact global 6th
        int cx = 0, cy = 0;
        for (int it = 0; it < HW / 256; ++it) {       // pass B: counts (L2-hot)
            float4 xv = ((const float4*)bxx)[it * 64 + lane];
            float4 yv = ((const float4*)bxy)[it * 64 + lane];
            cx += (fabsf(xt - xv.x) < e3) + (fabsf(xt - xv.y) < e3)
                + (fabsf(xt - xv.z) < e3) + (fabsf(xt - xv.w) < e3);
            cy += (fabsf(yt - yv.x) < e3) + (fabsf(yt - yv.y) < e3)
                + (fabsf(yt - yv.z) < e3) + (fabsf(yt - yv.w) < e3);
        }
        int pk3 = (cx << 16) | cy;
#pragma unroll
        for (int m = 1; m < 64; m <<= 1) pk3 += __shfl_xor(pk3, m);
        if (g == tg) { eps = e3; nx = pk3 >> 16; ny = pk3 & 0xffff; fell = true; }
    }

    if (!fell) {
        // nx: ok-check guarantees every fl|dx| < eps point is inside the
        // staged window -> pure LDS scan, zero global.
#pragma unroll 4
        for (int it = 0; it < WINB / 32; ++it) {
            float4 pp = f4[it * 16 + l];
            nx += (fabsf(xi - pp.x) < eps) + (fabsf(xi - pp.z) < eps);
        }
        // ny: interior bins by LDS prefix-diff + boundary scan from L2.
        int loB = binOf(yi - eps), hiB = binOf(yi + eps);
        int fLo = loB + 2, fHi = hiB - 2;
        if (fLo <= fHi) {
            if (l == 0) ny += pfy[fHi + 1] - pfy[fLo];
            int a0 = pfy[max(loB - 1, 0)], a1 = pfy[min(loB + 1, NBINS - 1) + 1];
            int b0 = pfy[max(hiB - 1, 0)], b1 = pfy[min(hiB + 1, NBINS - 1) + 1];
            for (int tt = a0 + l; tt < a1; tt += 16) ny += (fabsf(by[tt] - yi) < eps);
            for (int tt = b0 + l; tt < b1; tt += 16) ny += (fabsf(by[tt] - yi) < eps);
        } else {
            int a0 = pfy[max(loB - 1, 0)], a1 = pfy[min(hiB + 1, NBINS - 1) + 1];
            for (int tt = a0 + l; tt < a1; tt += 16) ny += (fabsf(by[tt] - yi) < eps);
        }
    }

    // Group-reduce; fallback rows carry full counts on l==0 only.
    if (fell && l != 0) { nx = 0; ny = 0; }
    int pk = (nx << 16) | ny;                 // totals <= 4096, no carry
#pragma unroll
    for (int m = 1; m < 16; m <<= 1) pk += __shfl_xor(pk, m);

    if (l == 0)
        red[q] = digammaf_dev((float)(pk >> 16)) + digammaf_dev((float)(pk & 0xffff));
    __syncthreads();

    if (threadIdx.x == 0) {
        float v = 0.f;
#pragma unroll
        for (int k = 0; k < ROWS_PER_BLOCK; ++k) v += red[k];
        (ws + WS_PART)[blockIdx.x] = v;
    }
}

// --------- Kernel 2: finalize ---------------------------------------------
__global__ void knnmi_final(const float* __restrict__ ws, float* __restrict__ out) {
    const float* partials = ws + WS_PART;
    const int w    = threadIdx.x >> 6;    // wave = channel
    const int lane = threadIdx.x & 63;
    float sum = (lane < BLOCKS_PER_CH) ? partials[w * BLOCKS_PER_CH + lane] : 0.f;
#pragma unroll
    for (int m = 32; m; m >>= 1) sum += __shfl_xor(sum, m);
    if (lane == 0) {
        float mi = digammaf_dev((float)KNN) + digammaf_dev((float)HW)
                 - sum / (float)HW;
        out[w] = fmaxf(mi, 0.f);
    }
}

extern "C" void kernel_launch(void* const* d_in, const int* in_sizes, int n_in,
                              void* d_out, int out_size, void* d_ws, size_t ws_size,
                              hipStream_t stream) {
    const float* x = (const float*)d_in[0];
    const float* y = (const float*)d_in[1];
    float* out = (float*)d_out;
    float* ws  = (float*)d_ws;   // all read regions fully rewritten every call

    knnmi_bucketize<<<2 * NCH, 256, 0, stream>>>(x, y, ws);
    knnmi_rows<<<NBLOCKS, TPB, 0, stream>>>(ws);
    knnmi_final<<<1, NCH * 64, 0, stream>>>(ws, out);
}